// Round 1
// baseline (88.860 us; speedup 1.0000x reference)
//
#include <hip/hip_runtime.h>

// AverageSpanExtractor: out[b,n,:] = mask[b,n] * mean(seq[b, start:end, :])
// B=8, S=2048, D=512, N=1024, width in [1,20].
//
// One 128-thread block per span; thread t owns float4 #t of the D=512 row.
// Round 3 changes vs round 2:
//  - Input guarantee: start in [0, S-20], so rows start..start+19 are ALWAYS
//    in-bounds. Load all 20 rows unconditionally -> 20 independent
//    global_load_dwordx4 in flight, ONE vmcnt wait (was: unroll-4 loop with a
//    serialized wait round per 4 rows -> latency-bound at ~3-5 L2 round trips
//    per block).
//  - Accumulate with a 0/1 select per row (w < width is wave-uniform ->
//    cndmask + fma, branch-free). Adds exact zeros for w >= width, so the
//    result is bit-identical to summing only the first `width` rows.
//  - Nontemporal store for the output: the 2 MB/XCD output stream was
//    evicting the XCD's 4 MB L2-resident seq slice.

#define DV4   128   // D / 4
#define BATCH 8
#define NSPAN 1024
#define SEQ_S 2048
#define WMAX  20

typedef float vf4 __attribute__((ext_vector_type(4)));

__global__ __launch_bounds__(128) void span_avg_kernel(
    const vf4* __restrict__ seq,    // [B, S, D/4]
    const int* __restrict__ spans,  // [B, N, 2] (start, exclusive end)
    const int* __restrict__ msk,    // [B, N]
    vf4*       __restrict__ out)    // [B, N, D/4]
{
    const int blk = blockIdx.x;        // 0..8191
    const int b   = blk & (BATCH - 1); // XCD-affine: b == XCD id (round-robin)
    const int n   = blk >> 3;
    const int sid = b * NSPAN + n;

    const int start = spans[2 * sid];
    const int width = spans[2 * sid + 1] - start;  // 1..20 guaranteed

    const int t = threadIdx.x;         // 0..127
    const vf4* row = seq + ((size_t)b * SEQ_S + (size_t)start) * DV4 + t;

    // All 20 loads issued back-to-back: full MLP, single wait.
    vf4 v[WMAX];
#pragma unroll
    for (int w = 0; w < WMAX; ++w)
        v[w] = row[w * DV4];           // compile-time constant indices -> regs

    vf4 a0 = (vf4)0.f, a1 = (vf4)0.f, a2 = (vf4)0.f, a3 = (vf4)0.f;
#pragma unroll
    for (int w = 0; w < WMAX; w += 4) {
        a0 += v[w + 0] * ((w + 0 < width) ? 1.f : 0.f);
        a1 += v[w + 1] * ((w + 1 < width) ? 1.f : 0.f);
        a2 += v[w + 2] * ((w + 2 < width) ? 1.f : 0.f);
        a3 += v[w + 3] * ((w + 3 < width) ? 1.f : 0.f);
    }

    vf4 acc = (a0 + a1) + (a2 + a3);
    const float scale = (float)msk[sid] / (float)width;
    acc *= scale;

    __builtin_nontemporal_store(acc, &out[(size_t)sid * DV4 + t]);
}

extern "C" void kernel_launch(void* const* d_in, const int* in_sizes, int n_in,
                              void* d_out, int out_size, void* d_ws, size_t ws_size,
                              hipStream_t stream) {
    const float* seq  = (const float*)d_in[0];   // [B,S,D] fp32
    const int*   sp   = (const int*)d_in[1];     // [B,N,2] int
    const int*   mask = (const int*)d_in[2];     // [B,N] int
    float*       out  = (float*)d_out;           // [B,N,D] fp32

    dim3 grid(BATCH * NSPAN);
    dim3 block(128);
    span_avg_kernel<<<grid, block, 0, stream>>>(
        (const vf4*)seq, sp, mask, (vf4*)out);
}

// Round 2
// 85.182 us; speedup vs baseline: 1.0432x; 1.0432x over previous
//
#include <hip/hip_runtime.h>

// AverageSpanExtractor: out[b,n,:] = mask[b,n] * mean(seq[b, start:end, :])
// B=8, S=2048, D=512, N=1024, width in [1,20].
//
// One 128-thread block per span; thread t owns float4 #t of the D=512 row.
// Round 4: decisive A/B between "kernel ~42us" and "harness-fill floor".
//  - Width-predicated load burst: `if (w < width)` is wave-uniform (width
//    comes from an s_load of the span table), so each load sits behind an
//    s_cbranch, NOT an exec-mask select. Taken loads issue back-to-back with
//    no intervening s_waitcnt (values are first used after the burst), so we
//    keep round-3's single-wait MLP while restoring round-2's width-bounded
//    traffic (avg 10.5 rows instead of 20 -> ~172 MB cache reads, half of
//    round 3).
//  - Skipped rows contribute exact 0.0f, so the sum is bit-identical to
//    summing only the first `width` rows.
//  - Keep XCD-affine batch swizzle (b = blk & 7: per-XCD 4 MB seq slice
//    stays L2-resident) and nontemporal output store (don't evict it).

#define DV4   128   // D / 4
#define BATCH 8
#define NSPAN 1024
#define SEQ_S 2048
#define WMAX  20

typedef float vf4 __attribute__((ext_vector_type(4)));

__global__ __launch_bounds__(128) void span_avg_kernel(
    const vf4* __restrict__ seq,    // [B, S, D/4]
    const int* __restrict__ spans,  // [B, N, 2] (start, exclusive end)
    const int* __restrict__ msk,    // [B, N]
    vf4*       __restrict__ out)    // [B, N, D/4]
{
    const int blk = blockIdx.x;        // 0..8191
    const int b   = blk & (BATCH - 1); // XCD-affine: b == XCD id (round-robin)
    const int n   = blk >> 3;
    const int sid = b * NSPAN + n;

    const int start = spans[2 * sid];
    const int width = spans[2 * sid + 1] - start;  // 1..20 guaranteed

    const int t = threadIdx.x;         // 0..127
    const vf4* row = seq + ((size_t)b * SEQ_S + (size_t)start) * DV4 + t;

    // Width-predicated load burst: uniform branches, no waits inside.
    vf4 v[WMAX];
#pragma unroll
    for (int w = 0; w < WMAX; ++w) {
        if (w < width) v[w] = row[w * DV4];
        else           v[w] = (vf4)0.f;
    }

    // Single wait region: 4-way tree accumulate of all 20 slots.
    vf4 a0 = (vf4)0.f, a1 = (vf4)0.f, a2 = (vf4)0.f, a3 = (vf4)0.f;
#pragma unroll
    for (int w = 0; w < WMAX; w += 4) {
        a0 += v[w + 0];
        a1 += v[w + 1];
        a2 += v[w + 2];
        a3 += v[w + 3];
    }

    vf4 acc = (a0 + a1) + (a2 + a3);
    const float scale = (float)msk[sid] / (float)width;
    acc *= scale;

    __builtin_nontemporal_store(acc, &out[(size_t)sid * DV4 + t]);
}

extern "C" void kernel_launch(void* const* d_in, const int* in_sizes, int n_in,
                              void* d_out, int out_size, void* d_ws, size_t ws_size,
                              hipStream_t stream) {
    const float* seq  = (const float*)d_in[0];   // [B,S,D] fp32
    const int*   sp   = (const int*)d_in[1];     // [B,N,2] int
    const int*   mask = (const int*)d_in[2];     // [B,N] int
    float*       out  = (float*)d_out;           // [B,N,D] fp32

    dim3 grid(BATCH * NSPAN);
    dim3 block(128);
    span_avg_kernel<<<grid, block, 0, stream>>>(
        (const vf4*)seq, sp, mask, (vf4*)out);
}